// Round 1
// baseline (886.363 us; speedup 1.0000x reference)
//
#include <hip/hip_runtime.h>
#include <hip/hip_bf16.h>

// MoE top-2 of 8: B=1024 tokens, M=10000, H=512.
// Sparse routing (only top-2 experts computed) + bf16 MFMA GEMMs.

#define B_TOK 1024
#define M_DIM 10000
#define E_NUM 8
#define H_DIM 512

typedef __attribute__((ext_vector_type(4))) float fx4;
typedef __attribute__((ext_vector_type(8))) short sx8;

#define LSTR 40  // LDS row stride in shorts: 32 data + 8 pad -> <=2-way bank conflicts (free)

__device__ __forceinline__ short f2bf(float f) {
  union { __hip_bfloat16 h; short s; } u;
  u.h = __float2bfloat16(f);
  return u.s;
}

__device__ __forceinline__ sx8 pack8(fx4 a, fx4 b) {
  sx8 r;
  r[0] = f2bf(a[0]); r[1] = f2bf(a[1]); r[2] = f2bf(a[2]); r[3] = f2bf(a[3]);
  r[4] = f2bf(b[0]); r[5] = f2bf(b[1]); r[6] = f2bf(b[2]); r[7] = f2bf(b[3]);
  return r;
}

__global__ void k_zero(int* cnt) {
  if (threadIdx.x < E_NUM) cnt[threadIdx.x] = 0;
}

// Router: f64-accumulated logits (tie safety vs numpy ref), top-2, softmax,
// per-token info + per-expert compacted (token, weight) lists.
__global__ __launch_bounds__(256) void k_router(
    const float* __restrict__ x, const float* __restrict__ Wr,
    int* __restrict__ cnt, int* __restrict__ tokAll, float* __restrict__ wAll,
    int* __restrict__ info, float* __restrict__ winfo)
{
  int b = blockIdx.x, t = threadIdx.x;
  const float* xr = x + (size_t)b * M_DIM;
  double acc[E_NUM];
#pragma unroll
  for (int e = 0; e < E_NUM; e++) acc[e] = 0.0;
  for (int m = t; m < M_DIM; m += 256) {
    float xv = xr[m];
#pragma unroll
    for (int e = 0; e < E_NUM; e++)
      acc[e] += (double)xv * (double)Wr[e * M_DIM + m];
  }
#pragma unroll
  for (int e = 0; e < E_NUM; e++) {
#pragma unroll
    for (int off = 32; off > 0; off >>= 1)
      acc[e] += __shfl_xor(acc[e], off);
  }
  __shared__ double part[4][E_NUM];
  int wave = t >> 6;
  if ((t & 63) == 0) {
    for (int e = 0; e < E_NUM; e++) part[wave][e] = acc[e];
  }
  __syncthreads();
  if (t == 0) {
    double lg[E_NUM];
    for (int e = 0; e < E_NUM; e++)
      lg[e] = part[0][e] + part[1][e] + part[2][e] + part[3][e];
    int i0 = 0;
    for (int e = 1; e < E_NUM; e++) if (lg[e] > lg[i0]) i0 = e;   // ties: lowest idx
    int i1 = (i0 == 0) ? 1 : 0;
    for (int e = 0; e < E_NUM; e++) if (e != i0 && lg[e] > lg[i1]) i1 = e;
    double ex = exp(lg[i1] - lg[i0]);
    float p0 = (float)(1.0 / (1.0 + ex));
    float p1 = (float)(ex / (1.0 + ex));
    info[b * 2] = i0; info[b * 2 + 1] = i1;
    winfo[b * 2] = p0; winfo[b * 2 + 1] = p1;
    int q0 = atomicAdd(&cnt[i0], 1);
    tokAll[i0 * B_TOK + q0] = b; wAll[i0 * B_TOK + q0] = p0;
    int q1 = atomicAdd(&cnt[i1], 1);
    tokAll[i1 * B_TOK + q1] = b; wAll[i1 * B_TOK + q1] = p1;
  }
}

// out[b][:] = w0*b2[e0][:] + w1*b2[e1][:]  (full overwrite; bias terms of combine)
__global__ __launch_bounds__(256) void k_init(
    const float* __restrict__ b2, const int* __restrict__ info,
    const float* __restrict__ winfo, float* __restrict__ out)
{
  int b = blockIdx.x, t = threadIdx.x;
  int e0 = info[b * 2], e1 = info[b * 2 + 1];
  float w0 = winfo[b * 2], w1 = winfo[b * 2 + 1];
  const fx4* p0 = (const fx4*)(b2 + (size_t)e0 * M_DIM);
  const fx4* p1 = (const fx4*)(b2 + (size_t)e1 * M_DIM);
  fx4* o = (fx4*)(out + (size_t)b * M_DIM);
  for (int i = t; i < M_DIM / 4; i += 256)
    o[i] = w0 * p0[i] + w1 * p1[i];
}

// GEMM1: h[tok,512] = relu(x_gather . W1[e]^T + b1[e]); 64x128 tile, BK=32.
__global__ __launch_bounds__(256) void k_mlp1(
    const float* __restrict__ x, const float* __restrict__ W1,
    const float* __restrict__ b1, const int* __restrict__ cnt,
    const int* __restrict__ tokAll, short* __restrict__ hbuf)
{
  int e = blockIdx.z, nt = blockIdx.y, tt = blockIdx.x;
  int ne = cnt[e], row0 = tt * 64;
  if (row0 >= ne) return;
  int nvalid = min(64, ne - row0);

  __shared__ __align__(16) short As[64 * LSTR];
  __shared__ __align__(16) short Bs[128 * LSTR];
  __shared__ int toks[64];

  int t = threadIdx.x;
  if (t < 64) toks[t] = tokAll[e * B_TOK + row0 + min(t, nvalid - 1)];
  __syncthreads();

  int arow = t >> 2, achk = t & 3;        // A: 64 rows x 4 chunks, 1 chunk/thread
  int brow = t >> 1, bchk = (t & 1) * 2;  // B: 128 rows x 4 chunks, 2 chunks/thread
  const float* xrow = x + (size_t)toks[arow] * M_DIM;
  const float* w1r = W1 + ((size_t)e * H_DIM + nt * 128 + brow) * M_DIM;

  int lane = t & 63, wave = t >> 6;
  int wr = wave >> 1, wc = wave & 1;      // wave tile: 32 rows x 64 cols
  int lrow = lane & 15, khalf = lane >> 4;

  fx4 z4 = {0.f, 0.f, 0.f, 0.f};
  fx4 acc[2][4];
#pragma unroll
  for (int m = 0; m < 2; m++)
#pragma unroll
    for (int n = 0; n < 4; n++) acc[m][n] = z4;

  const int NSTEP = (M_DIM + 31) / 32;  // 313 (tail 16 = exactly 2 zero chunks)
  sx8 zv = {0, 0, 0, 0, 0, 0, 0, 0};

  sx8 av, bv0, bv1;  // prologue (k=0 always in-bounds)
  av  = pack8(*(const fx4*)(xrow + achk * 8), *(const fx4*)(xrow + achk * 8 + 4));
  bv0 = pack8(*(const fx4*)(w1r + bchk * 8), *(const fx4*)(w1r + bchk * 8 + 4));
  bv1 = pack8(*(const fx4*)(w1r + bchk * 8 + 8), *(const fx4*)(w1r + bchk * 8 + 12));

  for (int ks = 0; ks < NSTEP; ks++) {
    __syncthreads();
    *(sx8*)(&As[arow * LSTR + achk * 8]) = av;
    *(sx8*)(&Bs[brow * LSTR + bchk * 8]) = bv0;
    *(sx8*)(&Bs[brow * LSTR + (bchk + 1) * 8]) = bv1;
    __syncthreads();
    if (ks + 1 < NSTEP) {  // prefetch next step; HBM latency hides under MFMA
      int k0 = (ks + 1) * 32;
      int ka = k0 + achk * 8;
      av = (ka + 8 <= M_DIM)
         ? pack8(*(const fx4*)(xrow + ka), *(const fx4*)(xrow + ka + 4)) : zv;
      int kb = k0 + bchk * 8;
      bv0 = (kb + 8 <= M_DIM)
          ? pack8(*(const fx4*)(w1r + kb), *(const fx4*)(w1r + kb + 4)) : zv;
      bv1 = (kb + 16 <= M_DIM)
          ? pack8(*(const fx4*)(w1r + kb + 8), *(const fx4*)(w1r + kb + 12)) : zv;
    }
    sx8 af[2], bf[4];
#pragma unroll
    for (int m = 0; m < 2; m++)
      af[m] = *(const sx8*)(&As[(wr * 32 + m * 16 + lrow) * LSTR + khalf * 8]);
#pragma unroll
    for (int n = 0; n < 4; n++)
      bf[n] = *(const sx8*)(&Bs[(wc * 64 + n * 16 + lrow) * LSTR + khalf * 8]);
#pragma unroll
    for (int m = 0; m < 2; m++)
#pragma unroll
      for (int n = 0; n < 4; n++)
        acc[m][n] = __builtin_amdgcn_mfma_f32_16x16x32_bf16(af[m], bf[n], acc[m][n], 0, 0, 0);
  }

#pragma unroll
  for (int m = 0; m < 2; m++)
#pragma unroll
    for (int n = 0; n < 4; n++) {
      int colg = nt * 128 + wc * 64 + n * 16 + lrow;
      float b1v = b1[e * H_DIM + colg];
#pragma unroll
      for (int r = 0; r < 4; r++) {
        int rl = wr * 32 + m * 16 + khalf * 4 + r;
        if (rl < nvalid) {
          float v = fmaxf(acc[m][n][r] + b1v, 0.f);
          hbuf[(size_t)(e * B_TOK + row0 + rl) * H_DIM + colg] = f2bf(v);
        }
      }
    }
}

// GEMM2: out[tok][:] += w * (h . W2[e]^T); 64x128 tile, K=512.
__global__ __launch_bounds__(256) void k_mlp2(
    const short* __restrict__ hbuf, const float* __restrict__ W2,
    const int* __restrict__ cnt, const int* __restrict__ tokAll,
    const float* __restrict__ wAll, float* __restrict__ out)
{
  int e = blockIdx.z, mt = blockIdx.y, tt = blockIdx.x;
  int ne = cnt[e], row0 = tt * 64;
  if (row0 >= ne) return;
  int nvalid = min(64, ne - row0);

  __shared__ __align__(16) short As[64 * LSTR];
  __shared__ __align__(16) short Bs[128 * LSTR];
  __shared__ int toks[64];
  __shared__ float wts[64];

  int t = threadIdx.x;
  if (t < 64) {
    toks[t] = tokAll[e * B_TOK + row0 + min(t, nvalid - 1)];
    wts[t] = (t < nvalid) ? wAll[e * B_TOK + row0 + t] : 0.f;
  }

  int arow = t >> 2, achk = t & 3;
  int brow = t >> 1, bchk = (t & 1) * 2;
  const short* hrow = hbuf + (size_t)(e * B_TOK + row0 + min(arow, nvalid - 1)) * H_DIM;
  int w2i = mt * 128 + brow;
  if (w2i >= M_DIM) w2i = M_DIM - 1;  // tail col-tile: staged junk, store-guarded
  const float* w2r = W2 + ((size_t)e * M_DIM + w2i) * H_DIM;

  int lane = t & 63, wave = t >> 6;
  int wr = wave >> 1, wc = wave & 1;
  int lrow = lane & 15, khalf = lane >> 4;

  fx4 z4 = {0.f, 0.f, 0.f, 0.f};
  fx4 acc[2][4];
#pragma unroll
  for (int m = 0; m < 2; m++)
#pragma unroll
    for (int n = 0; n < 4; n++) acc[m][n] = z4;

  sx8 av, bv0, bv1;  // h is already bf16 -> direct 16B copy
  av  = *(const sx8*)(hrow + achk * 8);
  bv0 = pack8(*(const fx4*)(w2r + bchk * 8), *(const fx4*)(w2r + bchk * 8 + 4));
  bv1 = pack8(*(const fx4*)(w2r + bchk * 8 + 8), *(const fx4*)(w2r + bchk * 8 + 12));

  for (int ks = 0; ks < 16; ks++) {  // K = 512 = 16 * 32, no tail
    __syncthreads();
    *(sx8*)(&As[arow * LSTR + achk * 8]) = av;
    *(sx8*)(&Bs[brow * LSTR + bchk * 8]) = bv0;
    *(sx8*)(&Bs[brow * LSTR + (bchk + 1) * 8]) = bv1;
    __syncthreads();
    if (ks + 1 < 16) {
      int k0 = (ks + 1) * 32;
      av  = *(const sx8*)(hrow + k0 + achk * 8);
      bv0 = pack8(*(const fx4*)(w2r + k0 + bchk * 8), *(const fx4*)(w2r + k0 + bchk * 8 + 4));
      bv1 = pack8(*(const fx4*)(w2r + k0 + bchk * 8 + 8), *(const fx4*)(w2r + k0 + bchk * 8 + 12));
    }
    sx8 af[2], bf[4];
#pragma unroll
    for (int m = 0; m < 2; m++)
      af[m] = *(const sx8*)(&As[(wr * 32 + m * 16 + lrow) * LSTR + khalf * 8]);
#pragma unroll
    for (int n = 0; n < 4; n++)
      bf[n] = *(const sx8*)(&Bs[(wc * 64 + n * 16 + lrow) * LSTR + khalf * 8]);
#pragma unroll
    for (int m = 0; m < 2; m++)
#pragma unroll
      for (int n = 0; n < 4; n++)
        acc[m][n] = __builtin_amdgcn_mfma_f32_16x16x32_bf16(af[m], bf[n], acc[m][n], 0, 0, 0);
  }

#pragma unroll
  for (int m = 0; m < 2; m++)
#pragma unroll
    for (int n = 0; n < 4; n++) {
      int colg = mt * 128 + wc * 64 + n * 16 + lrow;
      if (colg < M_DIM) {
#pragma unroll
        for (int r = 0; r < 4; r++) {
          int rl = wr * 32 + m * 16 + khalf * 4 + r;
          if (rl < nvalid)
            atomicAdd(out + (size_t)toks[rl] * M_DIM + colg, wts[rl] * acc[m][n][r]);
        }
      }
    }
}

extern "C" void kernel_launch(void* const* d_in, const int* in_sizes, int n_in,
                              void* d_out, int out_size, void* d_ws, size_t ws_size,
                              hipStream_t stream) {
  const float* x  = (const float*)d_in[0];
  const float* W1 = (const float*)d_in[1];
  const float* b1 = (const float*)d_in[2];
  const float* W2 = (const float*)d_in[3];
  const float* b2 = (const float*)d_in[4];
  const float* Wr = (const float*)d_in[5];
  float* out = (float*)d_out;

  // ws layout (~8.5 MB total)
  char* ws = (char*)d_ws;
  short* hbuf  = (short*)ws;                           // 8*1024*512*2 = 8388608 B
  int*   cnt   = (int*)(ws + 8388608);                 // 8 ints (64 B slot)
  int*   tokAll= (int*)(ws + 8388608 + 64);            // 8*1024 ints
  float* wAll  = (float*)(ws + 8388608 + 64 + 32768);  // 8*1024 floats
  int*   info  = (int*)(ws + 8388608 + 64 + 65536);    // 1024*2 ints
  float* winfo = (float*)(ws + 8388608 + 64 + 65536 + 8192); // 1024*2 floats

  k_zero<<<1, 64, 0, stream>>>(cnt);
  k_router<<<B_TOK, 256, 0, stream>>>(x, Wr, cnt, tokAll, wAll, info, winfo);
  k_init<<<B_TOK, 256, 0, stream>>>(b2, info, winfo, out);
  k_mlp1<<<dim3(16, 4, E_NUM), 256, 0, stream>>>(x, W1, b1, cnt, tokAll, hbuf);
  k_mlp2<<<dim3(16, 79, E_NUM), 256, 0, stream>>>(hbuf, W2, cnt, tokAll, wAll, out);
}

// Round 2
// 428.409 us; speedup vs baseline: 2.0690x; 2.0690x over previous
//
#include <hip/hip_runtime.h>
#include <hip/hip_bf16.h>

// MoE top-2 of 8: B=1024 tokens, M=10000, H=512.
// Sparse routing + bf16 MFMA GEMMs. Split-K GEMM1 for parallelism.

#define B_TOK 1024
#define M_DIM 10000
#define E_NUM 8
#define H_DIM 512

typedef __attribute__((ext_vector_type(4))) float fx4;
typedef __attribute__((ext_vector_type(8))) short sx8;
typedef __attribute__((ext_vector_type(4))) short sx4;

#define LSTR 40  // LDS row stride in shorts: 32 data + 8 pad

__device__ __forceinline__ short f2bf(float f) {
  union { __hip_bfloat16 h; short s; } u;
  u.h = __float2bfloat16(f);
  return u.s;
}

__device__ __forceinline__ sx8 pack8(fx4 a, fx4 b) {
  sx8 r;
  r[0] = f2bf(a[0]); r[1] = f2bf(a[1]); r[2] = f2bf(a[2]); r[3] = f2bf(a[3]);
  r[4] = f2bf(b[0]); r[5] = f2bf(b[1]); r[6] = f2bf(b[2]); r[7] = f2bf(b[3]);
  return r;
}

__global__ void k_zero(int* cnt) {
  if (threadIdx.x < E_NUM) cnt[threadIdx.x] = 0;
}

// Router: f64-accumulated logits (top-2 flip safety vs numpy ref), softmax,
// per-token info + per-expert compacted (token, weight) lists.
__global__ __launch_bounds__(256) void k_router(
    const float* __restrict__ x, const float* __restrict__ Wr,
    int* __restrict__ cnt, int* __restrict__ tokAll, float* __restrict__ wAll,
    int* __restrict__ info, float* __restrict__ winfo)
{
  int b = blockIdx.x, t = threadIdx.x;
  const float* xr = x + (size_t)b * M_DIM;
  double acc[E_NUM];
#pragma unroll
  for (int e = 0; e < E_NUM; e++) acc[e] = 0.0;
  for (int m = t; m < M_DIM; m += 256) {
    float xv = xr[m];
#pragma unroll
    for (int e = 0; e < E_NUM; e++)
      acc[e] += (double)xv * (double)Wr[e * M_DIM + m];
  }
#pragma unroll
  for (int e = 0; e < E_NUM; e++) {
#pragma unroll
    for (int off = 32; off > 0; off >>= 1)
      acc[e] += __shfl_xor(acc[e], off);
  }
  __shared__ double part[4][E_NUM];
  int wave = t >> 6;
  if ((t & 63) == 0) {
    for (int e = 0; e < E_NUM; e++) part[wave][e] = acc[e];
  }
  __syncthreads();
  if (t == 0) {
    double lg[E_NUM];
    for (int e = 0; e < E_NUM; e++)
      lg[e] = part[0][e] + part[1][e] + part[2][e] + part[3][e];
    int i0 = 0;
    for (int e = 1; e < E_NUM; e++) if (lg[e] > lg[i0]) i0 = e;
    int i1 = (i0 == 0) ? 1 : 0;
    for (int e = 0; e < E_NUM; e++) if (e != i0 && lg[e] > lg[i1]) i1 = e;
    double ex = exp(lg[i1] - lg[i0]);
    float p0 = (float)(1.0 / (1.0 + ex));
    float p1 = (float)(ex / (1.0 + ex));
    info[b * 2] = i0; info[b * 2 + 1] = i1;
    winfo[b * 2] = p0; winfo[b * 2 + 1] = p1;
    int q0 = atomicAdd(&cnt[i0], 1);
    tokAll[i0 * B_TOK + q0] = b; wAll[i0 * B_TOK + q0] = p0;
    int q1 = atomicAdd(&cnt[i1], 1);
    tokAll[i1 * B_TOK + q1] = b; wAll[i1 * B_TOK + q1] = p1;
  }
}

// out[b][:] = w0*b2[e0][:] + w1*b2[e1][:]  (full overwrite; bias terms of combine)
__global__ __launch_bounds__(256) void k_init(
    const float* __restrict__ b2, const int* __restrict__ info,
    const float* __restrict__ winfo, float* __restrict__ out)
{
  int b = blockIdx.x, t = threadIdx.x;
  int e0 = info[b * 2], e1 = info[b * 2 + 1];
  float w0 = winfo[b * 2], w1 = winfo[b * 2 + 1];
  const fx4* p0 = (const fx4*)(b2 + (size_t)e0 * M_DIM);
  const fx4* p1 = (const fx4*)(b2 + (size_t)e1 * M_DIM);
  fx4* o = (fx4*)(out + (size_t)b * M_DIM);
  for (int i = t; i < M_DIM / 4; i += 256)
    o[i] = w0 * p0[i] + w1 * p1[i];
}

// Zero the f32 split-K accumulator (8*1024*512 floats).
__global__ __launch_bounds__(256) void k_zeroh(float* __restrict__ hbuf32) {
  int i = blockIdx.x * 256 + threadIdx.x;
  fx4 z = {0.f, 0.f, 0.f, 0.f};
  ((fx4*)hbuf32)[i] = z;
}

// GEMM1 split-K: hbuf32[slot,512] += x_gather . W1[e]^T over a K chunk.
// Block tile: 128 tokens x 128 H cols, 4 waves (64x64 each), BK=32, KC=8.
__global__ __launch_bounds__(256) void k_mlp1(
    const float* __restrict__ x, const float* __restrict__ W1,
    const int* __restrict__ cnt, const int* __restrict__ tokAll,
    float* __restrict__ hbuf32)
{
  int e = blockIdx.z;
  int nt = blockIdx.y & 3, tt = blockIdx.y >> 2;  // H-tile (4), token-tile (8)
  int kc = blockIdx.x;                            // K chunk (8)
  int ne = cnt[e], row0 = tt * 128;
  if (row0 >= ne) return;
  int nvalid = min(128, ne - row0);

  __shared__ __align__(16) short As[128 * LSTR];
  __shared__ __align__(16) short Bs[128 * LSTR];
  __shared__ int toks[128];

  int t = threadIdx.x;
  if (t < 128) toks[t] = tokAll[e * B_TOK + row0 + min(t, nvalid - 1)];
  __syncthreads();

  int r4 = t >> 2, kch = t & 3;  // each thread: rows r4 & r4+64, K-chunk kch (8 f32)
  const float* xr0 = x + (size_t)toks[r4] * M_DIM + kch * 8;
  const float* xr1 = x + (size_t)toks[r4 + 64] * M_DIM + kch * 8;
  const float* wr0 = W1 + ((size_t)e * H_DIM + nt * 128 + r4) * M_DIM + kch * 8;
  const float* wr1 = W1 + ((size_t)e * H_DIM + nt * 128 + r4 + 64) * M_DIM + kch * 8;

  int lane = t & 63, wave = t >> 6;
  int wr = wave >> 1, wc = wave & 1;  // wave tile: 64 rows x 64 cols
  int lrow = lane & 15, khalf = lane >> 4;

  fx4 z4 = {0.f, 0.f, 0.f, 0.f};
  fx4 acc[4][4];
#pragma unroll
  for (int m = 0; m < 4; m++)
#pragma unroll
    for (int n = 0; n < 4; n++) acc[m][n] = z4;

  const int NSTEP = (M_DIM + 31) / 32;  // 313
  const int CH = 40;                    // 8 chunks x 40 = 320 >= 313
  int s0 = kc * CH, s1 = min(s0 + CH, NSTEP);
  sx8 zv = {0, 0, 0, 0, 0, 0, 0, 0};

  sx8 a0, a1, b0, b1v;
  {
    int k0 = s0 * 32 + kch * 8;
    bool ok = (k0 + 8 <= M_DIM);
    a0  = ok ? pack8(*(const fx4*)(xr0 + s0 * 32), *(const fx4*)(xr0 + s0 * 32 + 4)) : zv;
    a1  = ok ? pack8(*(const fx4*)(xr1 + s0 * 32), *(const fx4*)(xr1 + s0 * 32 + 4)) : zv;
    b0  = ok ? pack8(*(const fx4*)(wr0 + s0 * 32), *(const fx4*)(wr0 + s0 * 32 + 4)) : zv;
    b1v = ok ? pack8(*(const fx4*)(wr1 + s0 * 32), *(const fx4*)(wr1 + s0 * 32 + 4)) : zv;
  }

  for (int s = s0; s < s1; s++) {
    __syncthreads();
    *(sx8*)(&As[r4 * LSTR + kch * 8]) = a0;
    *(sx8*)(&As[(r4 + 64) * LSTR + kch * 8]) = a1;
    *(sx8*)(&Bs[r4 * LSTR + kch * 8]) = b0;
    *(sx8*)(&Bs[(r4 + 64) * LSTR + kch * 8]) = b1v;
    __syncthreads();
    if (s + 1 < s1) {
      int kn = (s + 1) * 32;
      bool ok = (kn + kch * 8 + 8 <= M_DIM);
      a0  = ok ? pack8(*(const fx4*)(xr0 + kn), *(const fx4*)(xr0 + kn + 4)) : zv;
      a1  = ok ? pack8(*(const fx4*)(xr1 + kn), *(const fx4*)(xr1 + kn + 4)) : zv;
      b0  = ok ? pack8(*(const fx4*)(wr0 + kn), *(const fx4*)(wr0 + kn + 4)) : zv;
      b1v = ok ? pack8(*(const fx4*)(wr1 + kn), *(const fx4*)(wr1 + kn + 4)) : zv;
    }
    sx8 af[4], bf[4];
#pragma unroll
    for (int m = 0; m < 4; m++)
      af[m] = *(const sx8*)(&As[(wr * 64 + m * 16 + lrow) * LSTR + khalf * 8]);
#pragma unroll
    for (int n = 0; n < 4; n++)
      bf[n] = *(const sx8*)(&Bs[(wc * 64 + n * 16 + lrow) * LSTR + khalf * 8]);
#pragma unroll
    for (int m = 0; m < 4; m++)
#pragma unroll
      for (int n = 0; n < 4; n++)
        acc[m][n] = __builtin_amdgcn_mfma_f32_16x16x32_bf16(af[m], bf[n], acc[m][n], 0, 0, 0);
  }

#pragma unroll
  for (int m = 0; m < 4; m++)
#pragma unroll
    for (int n = 0; n < 4; n++) {
      int colg = nt * 128 + wc * 64 + n * 16 + lrow;
#pragma unroll
      for (int r = 0; r < 4; r++) {
        int rl = wr * 64 + m * 16 + khalf * 4 + r;
        if (rl < nvalid)
          atomicAdd(&hbuf32[(size_t)(e * B_TOK + row0 + rl) * H_DIM + colg],
                    acc[m][n][r]);
      }
    }
}

// bias + relu + bf16 convert: hbuf32 -> hbuf
__global__ __launch_bounds__(256) void k_hact(
    const float* __restrict__ hbuf32, const float* __restrict__ b1,
    short* __restrict__ hbuf)
{
  int i4 = blockIdx.x * 256 + threadIdx.x;  // 4 floats per thread
  int i = i4 * 4;
  int col = i & (H_DIM - 1);
  int e = i >> 19;  // slot = i>>9; e = slot>>10
  fx4 h = *(const fx4*)(hbuf32 + i);
  fx4 bv = *(const fx4*)(b1 + e * H_DIM + col);
  sx4 o;
#pragma unroll
  for (int j = 0; j < 4; j++) o[j] = f2bf(fmaxf(h[j] + bv[j], 0.f));
  *(sx4*)(hbuf + i) = o;
}

// GEMM2: out[tok][:] += w * (h . W2[e]^T); 128x128 tile, 4 waves, K=512.
__global__ __launch_bounds__(256) void k_mlp2(
    const short* __restrict__ hbuf, const float* __restrict__ W2,
    const int* __restrict__ cnt, const int* __restrict__ tokAll,
    const float* __restrict__ wAll, float* __restrict__ out)
{
  int e = blockIdx.z, mt = blockIdx.y, tt = blockIdx.x;
  int ne = cnt[e], row0 = tt * 128;
  if (row0 >= ne) return;
  int nvalid = min(128, ne - row0);

  __shared__ __align__(16) short As[128 * LSTR];
  __shared__ __align__(16) short Bs[128 * LSTR];
  __shared__ int toks[128];
  __shared__ float wts[128];

  int t = threadIdx.x;
  if (t < 128) {
    toks[t] = tokAll[e * B_TOK + row0 + min(t, nvalid - 1)];
    wts[t] = (t < nvalid) ? wAll[e * B_TOK + row0 + t] : 0.f;
  }

  int r4 = t >> 2, kch = t & 3;
  const short* hr0 = hbuf + (size_t)(e * B_TOK + row0 + min(r4, nvalid - 1)) * H_DIM + kch * 8;
  const short* hr1 = hbuf + (size_t)(e * B_TOK + row0 + min(r4 + 64, nvalid - 1)) * H_DIM + kch * 8;
  const float* w20 = W2 + ((size_t)e * M_DIM + min(mt * 128 + r4, M_DIM - 1)) * H_DIM + kch * 8;
  const float* w21 = W2 + ((size_t)e * M_DIM + min(mt * 128 + r4 + 64, M_DIM - 1)) * H_DIM + kch * 8;

  int lane = t & 63, wave = t >> 6;
  int wr = wave >> 1, wc = wave & 1;
  int lrow = lane & 15, khalf = lane >> 4;

  fx4 z4 = {0.f, 0.f, 0.f, 0.f};
  fx4 acc[4][4];
#pragma unroll
  for (int m = 0; m < 4; m++)
#pragma unroll
    for (int n = 0; n < 4; n++) acc[m][n] = z4;

  sx8 a0, a1, b0, b1v;
  a0  = *(const sx8*)(hr0);
  a1  = *(const sx8*)(hr1);
  b0  = pack8(*(const fx4*)(w20), *(const fx4*)(w20 + 4));
  b1v = pack8(*(const fx4*)(w21), *(const fx4*)(w21 + 4));

  for (int s = 0; s < 16; s++) {  // K = 512 = 16 * 32
    __syncthreads();
    *(sx8*)(&As[r4 * LSTR + kch * 8]) = a0;
    *(sx8*)(&As[(r4 + 64) * LSTR + kch * 8]) = a1;
    *(sx8*)(&Bs[r4 * LSTR + kch * 8]) = b0;
    *(sx8*)(&Bs[(r4 + 64) * LSTR + kch * 8]) = b1v;
    __syncthreads();
    if (s + 1 < 16) {
      int kn = (s + 1) * 32;
      a0  = *(const sx8*)(hr0 + kn);
      a1  = *(const sx8*)(hr1 + kn);
      b0  = pack8(*(const fx4*)(w20 + kn), *(const fx4*)(w20 + kn + 4));
      b1v = pack8(*(const fx4*)(w21 + kn), *(const fx4*)(w21 + kn + 4));
    }
    sx8 af[4], bf[4];
#pragma unroll
    for (int m = 0; m < 4; m++)
      af[m] = *(const sx8*)(&As[(wr * 64 + m * 16 + lrow) * LSTR + khalf * 8]);
#pragma unroll
    for (int n = 0; n < 4; n++)
      bf[n] = *(const sx8*)(&Bs[(wc * 64 + n * 16 + lrow) * LSTR + khalf * 8]);
#pragma unroll
    for (int m = 0; m < 4; m++)
#pragma unroll
      for (int n = 0; n < 4; n++)
        acc[m][n] = __builtin_amdgcn_mfma_f32_16x16x32_bf16(af[m], bf[n], acc[m][n], 0, 0, 0);
  }

#pragma unroll
  for (int m = 0; m < 4; m++)
#pragma unroll
    for (int n = 0; n < 4; n++) {
      int colg = mt * 128 + wc * 64 + n * 16 + lrow;
      if (colg < M_DIM) {
#pragma unroll
        for (int r = 0; r < 4; r++) {
          int rl = wr * 64 + m * 16 + khalf * 4 + r;
          if (rl < nvalid)
            atomicAdd(out + (size_t)toks[rl] * M_DIM + colg, wts[rl] * acc[m][n][r]);
        }
      }
    }
}

extern "C" void kernel_launch(void* const* d_in, const int* in_sizes, int n_in,
                              void* d_out, int out_size, void* d_ws, size_t ws_size,
                              hipStream_t stream) {
  const float* x  = (const float*)d_in[0];
  const float* W1 = (const float*)d_in[1];
  const float* b1 = (const float*)d_in[2];
  const float* W2 = (const float*)d_in[3];
  const float* b2 = (const float*)d_in[4];
  const float* Wr = (const float*)d_in[5];
  float* out = (float*)d_out;

  // ws layout (~25.3 MB total)
  char* ws = (char*)d_ws;
  float* hbuf32 = (float*)ws;                              // 8*1024*512*4 = 16777216 B
  short* hbuf   = (short*)(ws + 16777216);                 // 8*1024*512*2 = 8388608 B
  int*   cnt    = (int*)(ws + 25165824);                   // 8 ints (64 B slot)
  int*   tokAll = (int*)(ws + 25165824 + 64);              // 8*1024 ints
  float* wAll   = (float*)(ws + 25165824 + 64 + 32768);    // 8*1024 floats
  int*   info   = (int*)(ws + 25165824 + 64 + 65536);      // 1024*2 ints
  float* winfo  = (float*)(ws + 25165824 + 64 + 65536 + 8192);

  k_zero<<<1, 64, 0, stream>>>(cnt);
  k_router<<<B_TOK, 256, 0, stream>>>(x, Wr, cnt, tokAll, wAll, info, winfo);
  k_init<<<B_TOK, 256, 0, stream>>>(b2, info, winfo, out);
  k_zeroh<<<4096, 256, 0, stream>>>(hbuf32);
  k_mlp1<<<dim3(8, 32, E_NUM), 256, 0, stream>>>(x, W1, cnt, tokAll, hbuf32);
  k_hact<<<4096, 256, 0, stream>>>(hbuf32, b1, hbuf);
  k_mlp2<<<dim3(8, 79, E_NUM), 256, 0, stream>>>(hbuf, W2, cnt, tokAll, wAll, out);
}

// Round 3
// 384.496 us; speedup vs baseline: 2.3053x; 1.1142x over previous
//
#include <hip/hip_runtime.h>
#include <hip/hip_bf16.h>

// MoE top-2 of 8: B=1024 tokens, M=10000, H=512.
// Sparse routing + bf16 MFMA GEMMs. NO global atomics on the data path:
//  - GEMM1: split-K into exclusive per-chunk partial buffers + reduce kernel.
//  - GEMM2: two ordered passes (top-1 then top-2) with plain RMW stores.

#define B_TOK 1024
#define M_DIM 10000
#define E_NUM 8
#define H_DIM 512
#define NSTEP 313  // ceil(10000/32)

typedef __attribute__((ext_vector_type(4))) float fx4;
typedef __attribute__((ext_vector_type(8))) short sx8;
typedef __attribute__((ext_vector_type(4))) short sx4;

#define LSTR 40  // LDS row stride in shorts: 32 data + 8 pad

__device__ __forceinline__ short f2bf(float f) {
  union { __hip_bfloat16 h; short s; } u;
  u.h = __float2bfloat16(f);
  return u.s;
}

__device__ __forceinline__ sx8 pack8(fx4 a, fx4 b) {
  sx8 r;
  r[0] = f2bf(a[0]); r[1] = f2bf(a[1]); r[2] = f2bf(a[2]); r[3] = f2bf(a[3]);
  r[4] = f2bf(b[0]); r[5] = f2bf(b[1]); r[6] = f2bf(b[2]); r[7] = f2bf(b[3]);
  return r;
}

__global__ void k_zero(int* cnt, int* cnt2) {
  if (threadIdx.x < E_NUM) cnt[threadIdx.x] = 0;
  if (threadIdx.x < 2 * E_NUM) cnt2[threadIdx.x] = 0;
}

// Router: f64-accumulated logits (top-2 flip safety vs numpy ref), softmax.
// Builds: per-expert combined list tokAll (A-gather order for GEMM1, pos q),
// and per-(expert, order) lists of q + weight for the two GEMM2 passes.
__global__ __launch_bounds__(256) void k_router(
    const float* __restrict__ x, const float* __restrict__ Wr,
    int* __restrict__ cnt, int* __restrict__ cnt2,
    int* __restrict__ tokAll, int* __restrict__ qlist2, float* __restrict__ wlist2)
{
  int b = blockIdx.x, t = threadIdx.x;
  const float* xr = x + (size_t)b * M_DIM;
  double acc[E_NUM];
#pragma unroll
  for (int e = 0; e < E_NUM; e++) acc[e] = 0.0;
  for (int m = t; m < M_DIM; m += 256) {
    float xv = xr[m];
#pragma unroll
    for (int e = 0; e < E_NUM; e++)
      acc[e] += (double)xv * (double)Wr[e * M_DIM + m];
  }
#pragma unroll
  for (int e = 0; e < E_NUM; e++) {
#pragma unroll
    for (int off = 32; off > 0; off >>= 1)
      acc[e] += __shfl_xor(acc[e], off);
  }
  __shared__ double part[4][E_NUM];
  int wave = t >> 6;
  if ((t & 63) == 0) {
    for (int e = 0; e < E_NUM; e++) part[wave][e] = acc[e];
  }
  __syncthreads();
  if (t == 0) {
    double lg[E_NUM];
    for (int e = 0; e < E_NUM; e++)
      lg[e] = part[0][e] + part[1][e] + part[2][e] + part[3][e];
    int i0 = 0;
    for (int e = 1; e < E_NUM; e++) if (lg[e] > lg[i0]) i0 = e;
    int i1 = (i0 == 0) ? 1 : 0;
    for (int e = 0; e < E_NUM; e++) if (e != i0 && lg[e] > lg[i1]) i1 = e;
    double ex = exp(lg[i1] - lg[i0]);
    float p0 = (float)(1.0 / (1.0 + ex));
    float p1 = (float)(ex / (1.0 + ex));
    int q0 = atomicAdd(&cnt[i0], 1);
    tokAll[i0 * B_TOK + q0] = b;
    int j0 = atomicAdd(&cnt2[i0 * 2 + 0], 1);
    qlist2[(i0 * 2 + 0) * B_TOK + j0] = q0;
    wlist2[(i0 * 2 + 0) * B_TOK + j0] = p0;
    int q1 = atomicAdd(&cnt[i1], 1);
    tokAll[i1 * B_TOK + q1] = b;
    int j1 = atomicAdd(&cnt2[i1 * 2 + 1], 1);
    qlist2[(i1 * 2 + 1) * B_TOK + j1] = q1;
    wlist2[(i1 * 2 + 1) * B_TOK + j1] = p1;
  }
}

// GEMM1 split-K, no atomics: partials[kc][slot][col] = x_gather . W1[e]^T
// over K chunk kc. Block tile: 128 tokens x 128 H cols, 4 waves (64x64).
__global__ __launch_bounds__(256) void k_mlp1(
    const float* __restrict__ x, const float* __restrict__ W1,
    const int* __restrict__ cnt, const int* __restrict__ tokAll,
    float* __restrict__ partials, int CH)
{
  int e = blockIdx.z;
  int tt = blockIdx.y >> 2, nt = blockIdx.y & 3;
  int kc = blockIdx.x;

  __shared__ int sh_ne, sh_eoff;
  __shared__ __align__(16) short As[128 * LSTR];
  __shared__ __align__(16) short Bs[128 * LSTR];
  __shared__ int toks[128];

  int t = threadIdx.x;
  if (t == 0) {
    int off = 0;
    for (int k = 0; k < e; k++) off += cnt[k];
    sh_eoff = off; sh_ne = cnt[e];
  }
  __syncthreads();
  int ne = sh_ne, eoff = sh_eoff, row0 = tt * 128;
  if (row0 >= ne) return;
  int nvalid = min(128, ne - row0);

  if (t < 128) toks[t] = tokAll[e * B_TOK + row0 + min(t, nvalid - 1)];
  __syncthreads();

  int r4 = t >> 2, kch = t & 3;  // each thread: rows r4 & r4+64, K-chunk kch (8 f32)
  const float* xr0 = x + (size_t)toks[r4] * M_DIM + kch * 8;
  const float* xr1 = x + (size_t)toks[r4 + 64] * M_DIM + kch * 8;
  const float* wr0 = W1 + ((size_t)e * H_DIM + nt * 128 + r4) * M_DIM + kch * 8;
  const float* wr1 = W1 + ((size_t)e * H_DIM + nt * 128 + r4 + 64) * M_DIM + kch * 8;

  int lane = t & 63, wave = t >> 6;
  int wr = wave >> 1, wc = wave & 1;  // wave tile: 64 rows x 64 cols
  int lrow = lane & 15, khalf = lane >> 4;

  fx4 z4 = {0.f, 0.f, 0.f, 0.f};
  fx4 acc[4][4];
#pragma unroll
  for (int m = 0; m < 4; m++)
#pragma unroll
    for (int n = 0; n < 4; n++) acc[m][n] = z4;

  int s0 = kc * CH, s1 = min(s0 + CH, NSTEP);
  sx8 zv = {0, 0, 0, 0, 0, 0, 0, 0};

  sx8 a0, a1, b0, b1v;
  {
    int k0 = s0 * 32 + kch * 8;
    bool ok = (k0 + 8 <= M_DIM);
    a0  = ok ? pack8(*(const fx4*)(xr0 + s0 * 32), *(const fx4*)(xr0 + s0 * 32 + 4)) : zv;
    a1  = ok ? pack8(*(const fx4*)(xr1 + s0 * 32), *(const fx4*)(xr1 + s0 * 32 + 4)) : zv;
    b0  = ok ? pack8(*(const fx4*)(wr0 + s0 * 32), *(const fx4*)(wr0 + s0 * 32 + 4)) : zv;
    b1v = ok ? pack8(*(const fx4*)(wr1 + s0 * 32), *(const fx4*)(wr1 + s0 * 32 + 4)) : zv;
  }

  for (int s = s0; s < s1; s++) {
    __syncthreads();
    *(sx8*)(&As[r4 * LSTR + kch * 8]) = a0;
    *(sx8*)(&As[(r4 + 64) * LSTR + kch * 8]) = a1;
    *(sx8*)(&Bs[r4 * LSTR + kch * 8]) = b0;
    *(sx8*)(&Bs[(r4 + 64) * LSTR + kch * 8]) = b1v;
    __syncthreads();
    if (s + 1 < s1) {
      int kn = (s + 1) * 32;
      bool ok = (kn + kch * 8 + 8 <= M_DIM);
      a0  = ok ? pack8(*(const fx4*)(xr0 + kn), *(const fx4*)(xr0 + kn + 4)) : zv;
      a1  = ok ? pack8(*(const fx4*)(xr1 + kn), *(const fx4*)(xr1 + kn + 4)) : zv;
      b0  = ok ? pack8(*(const fx4*)(wr0 + kn), *(const fx4*)(wr0 + kn + 4)) : zv;
      b1v = ok ? pack8(*(const fx4*)(wr1 + kn), *(const fx4*)(wr1 + kn + 4)) : zv;
    }
    sx8 af[4], bf[4];
#pragma unroll
    for (int m = 0; m < 4; m++)
      af[m] = *(const sx8*)(&As[(wr * 64 + m * 16 + lrow) * LSTR + khalf * 8]);
#pragma unroll
    for (int n = 0; n < 4; n++)
      bf[n] = *(const sx8*)(&Bs[(wc * 64 + n * 16 + lrow) * LSTR + khalf * 8]);
#pragma unroll
    for (int m = 0; m < 4; m++)
#pragma unroll
      for (int n = 0; n < 4; n++)
        acc[m][n] = __builtin_amdgcn_mfma_f32_16x16x32_bf16(af[m], bf[n], acc[m][n], 0, 0, 0);
  }

#pragma unroll
  for (int m = 0; m < 4; m++)
#pragma unroll
    for (int n = 0; n < 4; n++) {
      int colg = nt * 128 + wc * 64 + n * 16 + lrow;
#pragma unroll
      for (int r = 0; r < 4; r++) {
        int rl = wr * 64 + m * 16 + khalf * 4 + r;
        if (rl < nvalid) {
          int grow = eoff + row0 + rl;
          partials[((size_t)kc * 2048 + grow) * H_DIM + colg] = acc[m][n][r];
        }
      }
    }
}

// Reduce split-K partials + bias + relu -> bf16 hbuf. All 2048 slots valid.
__global__ __launch_bounds__(256) void k_hreduce(
    const float* __restrict__ partials, const float* __restrict__ b1,
    const int* __restrict__ cnt, short* __restrict__ hbuf, int KC)
{
  __shared__ int sc[E_NUM];
  int t = threadIdx.x;
  if (t < E_NUM) sc[t] = cnt[t];
  __syncthreads();
  int i = (blockIdx.x * 256 + t) * 4;
  int slot = i >> 9;
  int e = 0, off = 0;
  for (int k = 0; k < E_NUM - 1; k++) {
    if (slot >= off + sc[k]) { off += sc[k]; e++; } else break;
  }
  fx4 v = *(const fx4*)(partials + i);
  for (int kc = 1; kc < KC; kc++)
    v += *(const fx4*)(partials + (size_t)kc * 2048 * H_DIM + i);
  fx4 bv = *(const fx4*)(b1 + e * H_DIM + (i & (H_DIM - 1)));
  sx4 o;
#pragma unroll
  for (int j = 0; j < 4; j++) o[j] = f2bf(fmaxf(v[j] + bv[j], 0.f));
  *(sx4*)(hbuf + i) = o;
}

// GEMM2 pass (ord = 0: overwrite, ord = 1: accumulate).
// out[tok] (+)= w * (h . W2[e]^T + b2[e]); 128x128 tile, 4 waves, K=512.
__global__ __launch_bounds__(256) void k_mlp2(
    const short* __restrict__ hbuf, const float* __restrict__ W2,
    const float* __restrict__ b2, const int* __restrict__ cnt,
    const int* __restrict__ cnt2, const int* __restrict__ tokAll,
    const int* __restrict__ qlist2, const float* __restrict__ wlist2,
    float* __restrict__ out, int ord)
{
  int e = blockIdx.z, mt = blockIdx.y, tt = blockIdx.x;

  __shared__ int sh_ne2, sh_eoff;
  __shared__ __align__(16) short As[128 * LSTR];
  __shared__ __align__(16) short Bs[128 * LSTR];
  __shared__ int sl[128];
  __shared__ int tok2[128];
  __shared__ float wts[128];

  int t = threadIdx.x;
  if (t == 0) {
    int off = 0;
    for (int k = 0; k < e; k++) off += cnt[k];
    sh_eoff = off; sh_ne2 = cnt2[e * 2 + ord];
  }
  __syncthreads();
  int ne2 = sh_ne2, eoff = sh_eoff, row0 = tt * 128;
  if (row0 >= ne2) return;
  int nvalid = min(128, ne2 - row0);

  if (t < 128) {
    int j = row0 + min(t, nvalid - 1);
    int q = qlist2[(e * 2 + ord) * B_TOK + j];
    sl[t] = eoff + q;
    tok2[t] = tokAll[e * B_TOK + q];
    wts[t] = (t < nvalid) ? wlist2[(e * 2 + ord) * B_TOK + j] : 0.f;
  }
  __syncthreads();

  int r4 = t >> 2, kch = t & 3;
  const short* hr0 = hbuf + (size_t)sl[r4] * H_DIM + kch * 8;
  const short* hr1 = hbuf + (size_t)sl[r4 + 64] * H_DIM + kch * 8;
  const float* w20 = W2 + ((size_t)e * M_DIM + min(mt * 128 + r4, M_DIM - 1)) * H_DIM + kch * 8;
  const float* w21 = W2 + ((size_t)e * M_DIM + min(mt * 128 + r4 + 64, M_DIM - 1)) * H_DIM + kch * 8;

  int lane = t & 63, wave = t >> 6;
  int wr = wave >> 1, wc = wave & 1;
  int lrow = lane & 15, khalf = lane >> 4;

  fx4 z4 = {0.f, 0.f, 0.f, 0.f};
  fx4 acc[4][4];
#pragma unroll
  for (int m = 0; m < 4; m++)
#pragma unroll
    for (int n = 0; n < 4; n++) acc[m][n] = z4;

  sx8 a0, a1, b0, b1v;
  a0  = *(const sx8*)(hr0);
  a1  = *(const sx8*)(hr1);
  b0  = pack8(*(const fx4*)(w20), *(const fx4*)(w20 + 4));
  b1v = pack8(*(const fx4*)(w21), *(const fx4*)(w21 + 4));

  for (int s = 0; s < 16; s++) {  // K = 512 = 16 * 32
    __syncthreads();
    *(sx8*)(&As[r4 * LSTR + kch * 8]) = a0;
    *(sx8*)(&As[(r4 + 64) * LSTR + kch * 8]) = a1;
    *(sx8*)(&Bs[r4 * LSTR + kch * 8]) = b0;
    *(sx8*)(&Bs[(r4 + 64) * LSTR + kch * 8]) = b1v;
    __syncthreads();
    if (s + 1 < 16) {
      int kn = (s + 1) * 32;
      a0  = *(const sx8*)(hr0 + kn);
      a1  = *(const sx8*)(hr1 + kn);
      b0  = pack8(*(const fx4*)(w20 + kn), *(const fx4*)(w20 + kn + 4));
      b1v = pack8(*(const fx4*)(w21 + kn), *(const fx4*)(w21 + kn + 4));
    }
    sx8 af[4], bf[4];
#pragma unroll
    for (int m = 0; m < 4; m++)
      af[m] = *(const sx8*)(&As[(wr * 64 + m * 16 + lrow) * LSTR + khalf * 8]);
#pragma unroll
    for (int n = 0; n < 4; n++)
      bf[n] = *(const sx8*)(&Bs[(wc * 64 + n * 16 + lrow) * LSTR + khalf * 8]);
#pragma unroll
    for (int m = 0; m < 4; m++)
#pragma unroll
      for (int n = 0; n < 4; n++)
        acc[m][n] = __builtin_amdgcn_mfma_f32_16x16x32_bf16(af[m], bf[n], acc[m][n], 0, 0, 0);
  }

#pragma unroll
  for (int m = 0; m < 4; m++)
#pragma unroll
    for (int n = 0; n < 4; n++) {
      int colg = mt * 128 + wc * 64 + n * 16 + lrow;
      if (colg < M_DIM) {
        float b2v = b2[(size_t)e * M_DIM + colg];
#pragma unroll
        for (int r = 0; r < 4; r++) {
          int rl = wr * 64 + m * 16 + khalf * 4 + r;
          if (rl < nvalid) {
            float v = wts[rl] * (acc[m][n][r] + b2v);
            float* dst = out + (size_t)tok2[rl] * M_DIM + colg;
            if (ord == 0) *dst = v;
            else *dst += v;
          }
        }
      }
    }
}

extern "C" void kernel_launch(void* const* d_in, const int* in_sizes, int n_in,
                              void* d_out, int out_size, void* d_ws, size_t ws_size,
                              hipStream_t stream) {
  const float* x  = (const float*)d_in[0];
  const float* W1 = (const float*)d_in[1];
  const float* b1 = (const float*)d_in[2];
  const float* W2 = (const float*)d_in[3];
  const float* b2 = (const float*)d_in[4];
  const float* Wr = (const float*)d_in[5];
  float* out = (float*)d_out;

  // Adaptive split-K: KC=8 needs 32MB partials (ws >= 36MB), else KC=4 (16MB).
  int KC = (ws_size >= (size_t)36 * 1024 * 1024) ? 8 : 4;
  int CH = (NSTEP + KC - 1) / KC;

  char* p = (char*)d_ws;
  float* partials = (float*)p;               p += (size_t)KC * 2048 * H_DIM * 4;
  short* hbuf     = (short*)p;               p += (size_t)2048 * H_DIM * 2;
  int*   cnt      = (int*)p;                 p += 64;
  int*   cnt2     = (int*)p;                 p += 64;
  int*   tokAll   = (int*)p;                 p += E_NUM * B_TOK * 4;
  int*   qlist2   = (int*)p;                 p += 2 * E_NUM * B_TOK * 4;
  float* wlist2   = (float*)p;

  k_zero<<<1, 64, 0, stream>>>(cnt, cnt2);
  k_router<<<B_TOK, 256, 0, stream>>>(x, Wr, cnt, cnt2, tokAll, qlist2, wlist2);
  k_mlp1<<<dim3(KC, 12, E_NUM), 256, 0, stream>>>(x, W1, cnt, tokAll, partials, CH);
  k_hreduce<<<1024, 256, 0, stream>>>(partials, b1, cnt, hbuf, KC);
  k_mlp2<<<dim3(2, 79, E_NUM), 256, 0, stream>>>(hbuf, W2, b2, cnt, cnt2, tokAll,
                                                 qlist2, wlist2, out, 0);
  k_mlp2<<<dim3(2, 79, E_NUM), 256, 0, stream>>>(hbuf, W2, b2, cnt, cnt2, tokAll,
                                                 qlist2, wlist2, out, 1);
}

// Round 4
// 359.471 us; speedup vs baseline: 2.4657x; 1.0696x over previous
//
#include <hip/hip_runtime.h>
#include <hip/hip_bf16.h>

// MoE top-2 of 8: B=1024 tokens, M=10000, H=512.
// Sparse routing + bf16 MFMA GEMMs. No global atomics on the data path.
// R4: double-buffered LDS (1 barrier/step), early unconditional clamped loads,
// f32->bf16 pack moved AFTER the MFMA phase (off the load-latency chain).

#define B_TOK 1024
#define M_DIM 10000
#define E_NUM 8
#define H_DIM 512
#define NSTEP 313  // ceil(10000/32)

typedef __attribute__((ext_vector_type(4))) float fx4;
typedef __attribute__((ext_vector_type(8))) short sx8;
typedef __attribute__((ext_vector_type(4))) short sx4;

#define LSTR 40           // LDS row stride in shorts: 32 data + 8 pad
#define BUFS (256 * LSTR) // one dbuf half: 128 A rows + 128 B rows

__device__ __forceinline__ short f2bf(float f) {
  union { __hip_bfloat16 h; short s; } u;
  u.h = __float2bfloat16(f);
  return u.s;
}

__device__ __forceinline__ sx8 pack8(fx4 a, fx4 b) {
  sx8 r;
  r[0] = f2bf(a[0]); r[1] = f2bf(a[1]); r[2] = f2bf(a[2]); r[3] = f2bf(a[3]);
  r[4] = f2bf(b[0]); r[5] = f2bf(b[1]); r[6] = f2bf(b[2]); r[7] = f2bf(b[3]);
  return r;
}

__global__ void k_zero(int* cnt, int* cnt2) {
  if (threadIdx.x < E_NUM) cnt[threadIdx.x] = 0;
  if (threadIdx.x < 2 * E_NUM) cnt2[threadIdx.x] = 0;
}

// Router: f64-accumulated logits (top-2 flip safety vs numpy ref), softmax.
__global__ __launch_bounds__(256) void k_router(
    const float* __restrict__ x, const float* __restrict__ Wr,
    int* __restrict__ cnt, int* __restrict__ cnt2,
    int* __restrict__ tokAll, int* __restrict__ qlist2, float* __restrict__ wlist2)
{
  int b = blockIdx.x, t = threadIdx.x;
  const float* xr = x + (size_t)b * M_DIM;
  double acc[E_NUM];
#pragma unroll
  for (int e = 0; e < E_NUM; e++) acc[e] = 0.0;
  for (int m = t; m < M_DIM; m += 256) {
    float xv = xr[m];
#pragma unroll
    for (int e = 0; e < E_NUM; e++)
      acc[e] += (double)xv * (double)Wr[e * M_DIM + m];
  }
#pragma unroll
  for (int e = 0; e < E_NUM; e++) {
#pragma unroll
    for (int off = 32; off > 0; off >>= 1)
      acc[e] += __shfl_xor(acc[e], off);
  }
  __shared__ double part[4][E_NUM];
  int wave = t >> 6;
  if ((t & 63) == 0) {
    for (int e = 0; e < E_NUM; e++) part[wave][e] = acc[e];
  }
  __syncthreads();
  if (t == 0) {
    double lg[E_NUM];
    for (int e = 0; e < E_NUM; e++)
      lg[e] = part[0][e] + part[1][e] + part[2][e] + part[3][e];
    int i0 = 0;
    for (int e = 1; e < E_NUM; e++) if (lg[e] > lg[i0]) i0 = e;
    int i1 = (i0 == 0) ? 1 : 0;
    for (int e = 0; e < E_NUM; e++) if (e != i0 && lg[e] > lg[i1]) i1 = e;
    double ex = exp(lg[i1] - lg[i0]);
    float p0 = (float)(1.0 / (1.0 + ex));
    float p1 = (float)(ex / (1.0 + ex));
    int q0 = atomicAdd(&cnt[i0], 1);
    tokAll[i0 * B_TOK + q0] = b;
    int j0 = atomicAdd(&cnt2[i0 * 2 + 0], 1);
    qlist2[(i0 * 2 + 0) * B_TOK + j0] = q0;
    wlist2[(i0 * 2 + 0) * B_TOK + j0] = p0;
    int q1 = atomicAdd(&cnt[i1], 1);
    tokAll[i1 * B_TOK + q1] = b;
    int j1 = atomicAdd(&cnt2[i1 * 2 + 1], 1);
    qlist2[(i1 * 2 + 1) * B_TOK + j1] = q1;
    wlist2[(i1 * 2 + 1) * B_TOK + j1] = p1;
  }
}

// GEMM1 split-K, no atomics. Block tile: 128 tokens x 128 H, 4 waves (64x64).
__global__ __launch_bounds__(256) void k_mlp1(
    const float* __restrict__ x, const float* __restrict__ W1,
    const int* __restrict__ cnt, const int* __restrict__ tokAll,
    float* __restrict__ partials, int CH)
{
  int e = blockIdx.z;
  int tt = blockIdx.y >> 2, nt = blockIdx.y & 3;
  int kc = blockIdx.x;

  __shared__ int sh_ne, sh_eoff;
  __shared__ __align__(16) short SB[2 * BUFS];  // [buf][A rows 0..127 | B rows 128..255]
  __shared__ int toks[128];

  int t = threadIdx.x;
  if (t == 0) {
    int off = 0;
    for (int k = 0; k < e; k++) off += cnt[k];
    sh_eoff = off; sh_ne = cnt[e];
  }
  __syncthreads();
  int ne = sh_ne, eoff = sh_eoff, row0 = tt * 128;
  if (row0 >= ne) return;
  int nvalid = min(128, ne - row0);

  if (t < 128) toks[t] = tokAll[e * B_TOK + row0 + min(t, nvalid - 1)];
  __syncthreads();

  int r4 = t >> 2, kch = t & 3;  // thread stages rows r4 & r4+64 of A and B; k-chunk kch
  const float* xr0 = x + (size_t)toks[r4] * M_DIM;
  const float* xr1 = x + (size_t)toks[r4 + 64] * M_DIM;
  const float* wr0 = W1 + ((size_t)e * H_DIM + nt * 128 + r4) * M_DIM;
  const float* wr1 = W1 + ((size_t)e * H_DIM + nt * 128 + r4 + 64) * M_DIM;

  int lane = t & 63, wave = t >> 6;
  int wr = wave >> 1, wc = wave & 1;  // wave tile: 64 rows x 64 cols
  int lrow = lane & 15, khalf = lane >> 4;

  fx4 z4 = {0.f, 0.f, 0.f, 0.f};
  fx4 acc[4][4];
#pragma unroll
  for (int m = 0; m < 4; m++)
#pragma unroll
    for (int n = 0; n < 4; n++) acc[m][n] = z4;

  int s0 = kc * CH, s1 = min(s0 + CH, NSTEP);
  sx8 zv = {0, 0, 0, 0, 0, 0, 0, 0};

  // prologue: stage step s0 into buf 0
  {
    int off = s0 * 32 + kch * 8;
    int oc = min(off, M_DIM - 8);
    bool ok = (off + 8 <= M_DIM);
    fx4 A0 = *(const fx4*)(xr0 + oc), A0b = *(const fx4*)(xr0 + oc + 4);
    fx4 A1 = *(const fx4*)(xr1 + oc), A1b = *(const fx4*)(xr1 + oc + 4);
    fx4 B0 = *(const fx4*)(wr0 + oc), B0b = *(const fx4*)(wr0 + oc + 4);
    fx4 B1 = *(const fx4*)(wr1 + oc), B1b = *(const fx4*)(wr1 + oc + 4);
    sx8 pa0 = ok ? pack8(A0, A0b) : zv;
    sx8 pa1 = ok ? pack8(A1, A1b) : zv;
    sx8 pb0 = ok ? pack8(B0, B0b) : zv;
    sx8 pb1 = ok ? pack8(B1, B1b) : zv;
    *(sx8*)(&SB[r4 * LSTR + kch * 8]) = pa0;
    *(sx8*)(&SB[(r4 + 64) * LSTR + kch * 8]) = pa1;
    *(sx8*)(&SB[(128 + r4) * LSTR + kch * 8]) = pb0;
    *(sx8*)(&SB[(128 + r4 + 64) * LSTR + kch * 8]) = pb1;
  }
  __syncthreads();

  int c = 0;
  for (int s = s0; s < s1; s++) {
    // 1) issue next-step loads NOW (unconditional, clamped) — in flight across MFMA
    int off = (s + 1) * 32 + kch * 8;
    int oc = min(off, M_DIM - 8);
    bool okn = (off + 8 <= M_DIM);
    fx4 A0 = *(const fx4*)(xr0 + oc), A0b = *(const fx4*)(xr0 + oc + 4);
    fx4 A1 = *(const fx4*)(xr1 + oc), A1b = *(const fx4*)(xr1 + oc + 4);
    fx4 B0 = *(const fx4*)(wr0 + oc), B0b = *(const fx4*)(wr0 + oc + 4);
    fx4 B1 = *(const fx4*)(wr1 + oc), B1b = *(const fx4*)(wr1 + oc + 4);

    // 2) ds_read fragments + MFMA on buf[c]
    int bo = c * BUFS;
    sx8 af[4], bf[4];
#pragma unroll
    for (int m = 0; m < 4; m++)
      af[m] = *(const sx8*)(&SB[bo + (wr * 64 + m * 16 + lrow) * LSTR + khalf * 8]);
#pragma unroll
    for (int n = 0; n < 4; n++)
      bf[n] = *(const sx8*)(&SB[bo + (128 + wc * 64 + n * 16 + lrow) * LSTR + khalf * 8]);
#pragma unroll
    for (int m = 0; m < 4; m++)
#pragma unroll
      for (int n = 0; n < 4; n++)
        acc[m][n] = __builtin_amdgcn_mfma_f32_16x16x32_bf16(af[m], bf[n], acc[m][n], 0, 0, 0);

    // 3) pack (waits for loads here, after MFMA) + write the other buffer
    if (s + 1 < s1) {
      int wo = (c ^ 1) * BUFS;
      sx8 pa0 = okn ? pack8(A0, A0b) : zv;
      sx8 pa1 = okn ? pack8(A1, A1b) : zv;
      sx8 pb0 = okn ? pack8(B0, B0b) : zv;
      sx8 pb1 = okn ? pack8(B1, B1b) : zv;
      *(sx8*)(&SB[wo + r4 * LSTR + kch * 8]) = pa0;
      *(sx8*)(&SB[wo + (r4 + 64) * LSTR + kch * 8]) = pa1;
      *(sx8*)(&SB[wo + (128 + r4) * LSTR + kch * 8]) = pb0;
      *(sx8*)(&SB[wo + (128 + r4 + 64) * LSTR + kch * 8]) = pb1;
    }
    __syncthreads();
    c ^= 1;
  }

#pragma unroll
  for (int m = 0; m < 4; m++)
#pragma unroll
    for (int n = 0; n < 4; n++) {
      int colg = nt * 128 + wc * 64 + n * 16 + lrow;
#pragma unroll
      for (int r = 0; r < 4; r++) {
        int rl = wr * 64 + m * 16 + khalf * 4 + r;
        if (rl < nvalid) {
          int grow = eoff + row0 + rl;
          partials[((size_t)kc * 2048 + grow) * H_DIM + colg] = acc[m][n][r];
        }
      }
    }
}

// Reduce split-K partials + bias + relu -> bf16 hbuf.
__global__ __launch_bounds__(256) void k_hreduce(
    const float* __restrict__ partials, const float* __restrict__ b1,
    const int* __restrict__ cnt, short* __restrict__ hbuf, int KC)
{
  __shared__ int sc[E_NUM];
  int t = threadIdx.x;
  if (t < E_NUM) sc[t] = cnt[t];
  __syncthreads();
  int i = (blockIdx.x * 256 + t) * 4;
  int slot = i >> 9;
  int e = 0, off = 0;
  for (int k = 0; k < E_NUM - 1; k++) {
    if (slot >= off + sc[k]) { off += sc[k]; e++; } else break;
  }
  fx4 v = *(const fx4*)(partials + i);
  for (int kc = 1; kc < KC; kc++)
    v += *(const fx4*)(partials + (size_t)kc * 2048 * H_DIM + i);
  fx4 bv = *(const fx4*)(b1 + e * H_DIM + (i & (H_DIM - 1)));
  sx4 o;
#pragma unroll
  for (int j = 0; j < 4; j++) o[j] = f2bf(fmaxf(v[j] + bv[j], 0.f));
  *(sx4*)(hbuf + i) = o;
}

// GEMM2 pass (ord=0: overwrite, ord=1: accumulate). 128x128 tile, K=512.
__global__ __launch_bounds__(256) void k_mlp2(
    const short* __restrict__ hbuf, const float* __restrict__ W2,
    const float* __restrict__ b2, const int* __restrict__ cnt,
    const int* __restrict__ cnt2, const int* __restrict__ tokAll,
    const int* __restrict__ qlist2, const float* __restrict__ wlist2,
    float* __restrict__ out, int ord)
{
  int e = blockIdx.z, mt = blockIdx.y, tt = blockIdx.x;

  __shared__ int sh_ne2, sh_eoff;
  __shared__ __align__(16) short SB[2 * BUFS];
  __shared__ int sl[128];
  __shared__ int tok2[128];
  __shared__ float wts[128];

  int t = threadIdx.x;
  if (t == 0) {
    int off = 0;
    for (int k = 0; k < e; k++) off += cnt[k];
    sh_eoff = off; sh_ne2 = cnt2[e * 2 + ord];
  }
  __syncthreads();
  int ne2 = sh_ne2, eoff = sh_eoff, row0 = tt * 128;
  if (row0 >= ne2) return;
  int nvalid = min(128, ne2 - row0);

  if (t < 128) {
    int j = row0 + min(t, nvalid - 1);
    int q = qlist2[(e * 2 + ord) * B_TOK + j];
    sl[t] = eoff + q;
    tok2[t] = tokAll[e * B_TOK + q];
    wts[t] = (t < nvalid) ? wlist2[(e * 2 + ord) * B_TOK + j] : 0.f;
  }
  __syncthreads();

  int r4 = t >> 2, kch = t & 3;
  const short* hr0 = hbuf + (size_t)sl[r4] * H_DIM;
  const short* hr1 = hbuf + (size_t)sl[r4 + 64] * H_DIM;
  const float* w20 = W2 + ((size_t)e * M_DIM + min(mt * 128 + r4, M_DIM - 1)) * H_DIM;
  const float* w21 = W2 + ((size_t)e * M_DIM + min(mt * 128 + r4 + 64, M_DIM - 1)) * H_DIM;

  int lane = t & 63, wave = t >> 6;
  int wr = wave >> 1, wc = wave & 1;
  int lrow = lane & 15, khalf = lane >> 4;

  fx4 z4 = {0.f, 0.f, 0.f, 0.f};
  fx4 acc[4][4];
#pragma unroll
  for (int m = 0; m < 4; m++)
#pragma unroll
    for (int n = 0; n < 4; n++) acc[m][n] = z4;

  // prologue: stage step 0 into buf 0
  {
    int off = kch * 8;
    sx8 pa0 = *(const sx8*)(hr0 + off);
    sx8 pa1 = *(const sx8*)(hr1 + off);
    fx4 B0 = *(const fx4*)(w20 + off), B0b = *(const fx4*)(w20 + off + 4);
    fx4 B1 = *(const fx4*)(w21 + off), B1b = *(const fx4*)(w21 + off + 4);
    *(sx8*)(&SB[r4 * LSTR + kch * 8]) = pa0;
    *(sx8*)(&SB[(r4 + 64) * LSTR + kch * 8]) = pa1;
    *(sx8*)(&SB[(128 + r4) * LSTR + kch * 8]) = pack8(B0, B0b);
    *(sx8*)(&SB[(128 + r4 + 64) * LSTR + kch * 8]) = pack8(B1, B1b);
  }
  __syncthreads();

  int c = 0;
  for (int s = 0; s < 16; s++) {  // K = 512 = 16 * 32
    int off = min((s + 1) * 32 + kch * 8, H_DIM - 8);  // clamp: last prefetch discarded
    sx8 pa0 = *(const sx8*)(hr0 + off);
    sx8 pa1 = *(const sx8*)(hr1 + off);
    fx4 B0 = *(const fx4*)(w20 + off), B0b = *(const fx4*)(w20 + off + 4);
    fx4 B1 = *(const fx4*)(w21 + off), B1b = *(const fx4*)(w21 + off + 4);

    int bo = c * BUFS;
    sx8 af[4], bf[4];
#pragma unroll
    for (int m = 0; m < 4; m++)
      af[m] = *(const sx8*)(&SB[bo + (wr * 64 + m * 16 + lrow) * LSTR + khalf * 8]);
#pragma unroll
    for (int n = 0; n < 4; n++)
      bf[n] = *(const sx8*)(&SB[bo + (128 + wc * 64 + n * 16 + lrow) * LSTR + khalf * 8]);
#pragma unroll
    for (int m = 0; m < 4; m++)
#pragma unroll
      for (int n = 0; n < 4; n++)
        acc[m][n] = __builtin_amdgcn_mfma_f32_16x16x32_bf16(af[m], bf[n], acc[m][n], 0, 0, 0);

    if (s + 1 < 16) {
      int wo = (c ^ 1) * BUFS;
      *(sx8*)(&SB[wo + r4 * LSTR + kch * 8]) = pa0;
      *(sx8*)(&SB[wo + (r4 + 64) * LSTR + kch * 8]) = pa1;
      *(sx8*)(&SB[wo + (128 + r4) * LSTR + kch * 8]) = pack8(B0, B0b);
      *(sx8*)(&SB[wo + (128 + r4 + 64) * LSTR + kch * 8]) = pack8(B1, B1b);
    }
    __syncthreads();
    c ^= 1;
  }

#pragma unroll
  for (int m = 0; m < 4; m++)
#pragma unroll
    for (int n = 0; n < 4; n++) {
      int colg = mt * 128 + wc * 64 + n * 16 + lrow;
      if (colg < M_DIM) {
        float b2v = b2[(size_t)e * M_DIM + colg];
#pragma unroll
        for (int r = 0; r < 4; r++) {
          int rl = wr * 64 + m * 16 + khalf * 4 + r;
          if (rl < nvalid) {
            float v = wts[rl] * (acc[m][n][r] + b2v);
            float* dst = out + (size_t)tok2[rl] * M_DIM + colg;
            if (ord == 0) *dst = v;
            else *dst += v;
          }
        }
      }
    }
}

extern "C" void kernel_launch(void* const* d_in, const int* in_sizes, int n_in,
                              void* d_out, int out_size, void* d_ws, size_t ws_size,
                              hipStream_t stream) {
  const float* x  = (const float*)d_in[0];
  const float* W1 = (const float*)d_in[1];
  const float* b1 = (const float*)d_in[2];
  const float* W2 = (const float*)d_in[3];
  const float* b2 = (const float*)d_in[4];
  const float* Wr = (const float*)d_in[5];
  float* out = (float*)d_out;

  int KC = (ws_size >= (size_t)36 * 1024 * 1024) ? 8 : 4;
  int CH = (NSTEP + KC - 1) / KC;

  char* p = (char*)d_ws;
  float* partials = (float*)p;               p += (size_t)KC * 2048 * H_DIM * 4;
  short* hbuf     = (short*)p;               p += (size_t)2048 * H_DIM * 2;
  int*   cnt      = (int*)p;                 p += 64;
  int*   cnt2     = (int*)p;                 p += 64;
  int*   tokAll   = (int*)p;                 p += E_NUM * B_TOK * 4;
  int*   qlist2   = (int*)p;                 p += 2 * E_NUM * B_TOK * 4;
  float* wlist2   = (float*)p;

  k_zero<<<1, 64, 0, stream>>>(cnt, cnt2);
  k_router<<<B_TOK, 256, 0, stream>>>(x, Wr, cnt, cnt2, tokAll, qlist2, wlist2);
  k_mlp1<<<dim3(KC, 12, E_NUM), 256, 0, stream>>>(x, W1, cnt, tokAll, partials, CH);
  k_hreduce<<<1024, 256, 0, stream>>>(partials, b1, cnt, hbuf, KC);
  k_mlp2<<<dim3(2, 79, E_NUM), 256, 0, stream>>>(hbuf, W2, b2, cnt, cnt2, tokAll,
                                                 qlist2, wlist2, out, 0);
  k_mlp2<<<dim3(2, 79, E_NUM), 256, 0, stream>>>(hbuf, W2, b2, cnt, cnt2, tokAll,
                                                 qlist2, wlist2, out, 1);
}